// Round 8
// baseline (260.006 us; speedup 1.0000x reference)
//
#include <hip/hip_runtime.h>
#include <hip/hip_bf16.h>
#include <math.h>

#define M_TOTAL 16384   // B*S = 4*4096
#define D_MODEL 1024
#define N_QKV   3072
#define CURV    0.15f
#define EPS_F   1e-6f

typedef __attribute__((ext_vector_type(8))) short short8v;
typedef __attribute__((ext_vector_type(4))) float f32x4;

__device__ __forceinline__ void gl_lds16(const void* g, void* l) {
    __builtin_amdgcn_global_load_lds(
        (const __attribute__((address_space(1))) void*)g,
        (__attribute__((address_space(3))) void*)l, 16, 0, 0);
}
__device__ __forceinline__ unsigned short f2bf_bits(float x) {
    __hip_bfloat16 t = __float2bfloat16(x);
    return *(unsigned short*)&t;
}
__device__ __forceinline__ float bf2f(unsigned short u) {
    return __uint_as_float(((unsigned)u) << 16);
}

// ---------------------------------------------------------------------------
// cast fp32 -> bf16, 4 elems/thread
// ---------------------------------------------------------------------------
__global__ __launch_bounds__(256)
void cast_f32_bf16(const float* __restrict__ in, unsigned short* __restrict__ out,
                   int ngroups)
{
    int i = blockIdx.x * 256 + threadIdx.x;
    if (i >= ngroups) return;
    float4 u = ((const float4*)in)[i];
    ushort4 r;
    r.x = f2bf_bits(u.x); r.y = f2bf_bits(u.y);
    r.z = f2bf_bits(u.z); r.w = f2bf_bits(u.w);
    ((ushort4*)out)[i] = r;
}

// ---------------------------------------------------------------------------
// transpose + cast: W[K][N] fp32  ->  Wt[N][K] bf16.
// ---------------------------------------------------------------------------
__global__ __launch_bounds__(256)
void transpose_cast(const float* __restrict__ W, unsigned short* __restrict__ Wt,
                    int K, int N)
{
    __shared__ float tile[32][33];
    const int n0 = blockIdx.x * 32;
    const int k0 = blockIdx.y * 32;
    const int tx = threadIdx.x & 31;
    const int ty = threadIdx.x >> 5;
    #pragma unroll
    for (int i = 0; i < 32; i += 8)
        tile[ty + i][tx] = W[(size_t)(k0 + ty + i) * N + n0 + tx];
    __syncthreads();
    #pragma unroll
    for (int i = 0; i < 32; i += 8)
        Wt[(size_t)(n0 + ty + i) * K + k0 + tx] = f2bf_bits(tile[tx][ty + i]);
}

// ---------------------------------------------------------------------------
// 256x256 bf16 MFMA GEMM, BK=32, 256 thr = 4 waves (2x2), wave-tile 128x128.
// Rationale (R8): MfmaUtil was pinned at ~35% by LDS traffic: per K-tile/CU
// the old 8-wave 128x64 wave-tiles needed 192 ds_read_b128 (192 KB); the
// 128x128 wave-tile needs 64 (64 KB) for the same MFMA work -> MFMA-bound.
// acc[8][8] f32x4 = 256 regs (AGPR) + 64 frag VGPR -> 1 wave/SIMD via
// __launch_bounds__(256,1); ILP (64 independent MFMAs + prefetched reads)
// saturates the matrix pipe without co-waves. R7's measured-conflict-free
// swizzle (phys chunk = k_chunk ^ ((row>>1)&3)) reused byte-for-byte.
// 64 KiB LDS double buffer; simple 2-barrier loop; counted vmcnt(8).
// ---------------------------------------------------------------------------
template<int OUT_BF16>
__global__ __launch_bounds__(256, 1)
void gemm_wt128(const unsigned short* __restrict__ A,
                const unsigned short* __restrict__ Bt,
                const float* __restrict__ bias,
                void* __restrict__ Cout,
                int M, int N, int K, int nbx)
{
    constexpr int ABYTES = 256 * 64;         // 16 KB per region per buffer
    constexpr int BUFB   = 2 * ABYTES;       // 32 KB (A + B)
    __shared__ __align__(16) char smem[2 * BUFB];

    const int t    = threadIdx.x;
    const int w    = t >> 6;
    const int lane = t & 63;
    const int wm   = w >> 1;                 // 0..1
    const int wn   = w & 1;                  // 0..1
    const int lr   = lane & 15;
    const int hi   = lane >> 4;              // 0..3

    // bijective XCD chunk swizzle (gridDim.x % 8 == 0)
    const int nwg  = gridDim.x;
    const int orig = blockIdx.x;
    const int wgid = (orig & 7) * (nwg >> 3) + (orig >> 3);
    const int by = wgid / nbx, bx = wgid % nbx;
    const int bm0 = by * 256, bn0 = bx * 256;

    const int nt  = K >> 5;
    const size_t K64 = (size_t)64 * K;

    // staging: region = 256 rows x 4 chunks(16B) = 1024 chunks; 4 calls of
    // 256 thr x 16B. call j covers rows 64j..64j+63. LDS dest linear chunk
    // t + 256j; source col pre-swizzled (rule #21), R7-proven pattern.
    const int srow = t >> 2;                              // 0..63
    const int scol = ((t & 3) ^ ((t >> 3) & 3)) << 3;     // elem offset
    const unsigned short* Ag = A  + (size_t)(bm0 + srow) * K + scol;
    const unsigned short* Bg = Bt + (size_t)(bn0 + srow) * K + scol;
    const int wb = w << 10;                  // wave-uniform 1KB slot

    auto STAGE = [&](int tile) {
        const size_t ko = (size_t)tile << 5;
        char* bb = smem + (tile & 1) * BUFB;
        #pragma unroll
        for (int j = 0; j < 4; ++j)
            gl_lds16(Ag + ko + j * K64, bb + j * 4096 + wb);
        #pragma unroll
        for (int j = 0; j < 4; ++j)
            gl_lds16(Bg + ko + j * K64, bb + ABYTES + j * 4096 + wb);
    };

    f32x4 acc[8][8] = {};

    // ---- prologue: stage tiles 0,1; tile 0 resident ----
    STAGE(0); STAGE(1);
    asm volatile("s_waitcnt vmcnt(8)" ::: "memory");
    __builtin_amdgcn_s_barrier();

    for (int T = 0; T < nt; ++T) {
        const char* base = smem + (T & 1) * BUFB;
        short8v a[8], b[8];
        #pragma unroll
        for (int m = 0; m < 8; ++m) {
            const int row = wm * 128 + m * 16 + lr;
            a[m] = *(const short8v*)(base + row * 64
                                     + ((hi ^ ((row >> 1) & 3)) << 4));
        }
        #pragma unroll
        for (int n = 0; n < 8; ++n) {
            const int row = wn * 128 + n * 16 + lr;
            b[n] = *(const short8v*)(base + ABYTES + row * 64
                                     + ((hi ^ ((row >> 1) & 3)) << 4));
        }
        #pragma unroll
        for (int n = 0; n < 8; ++n)
            #pragma unroll
            for (int m = 0; m < 8; ++m)
                acc[m][n] = __builtin_amdgcn_mfma_f32_16x16x32_bf16(
                                a[m], b[n], acc[m][n], 0, 0, 0);
        __builtin_amdgcn_s_barrier();        // all waves' buf reads retired
        if (T + 2 < nt) {
            STAGE(T + 2);
            asm volatile("s_waitcnt vmcnt(8)" ::: "memory");
        } else {
            asm volatile("s_waitcnt vmcnt(0)" ::: "memory");
        }
        __builtin_amdgcn_s_barrier();        // tile T+1 resident
    }

    // ---- epilogue: C/D layout col=lane&15, row=hi*4+j ----
    const int r0 = bm0 + wm * 128 + hi * 4;
    const int cb = bn0 + wn * 128 + lr;
    float bv[8];
    #pragma unroll
    for (int n = 0; n < 8; ++n) bv[n] = bias[cb + n * 16];
    if (OUT_BF16) {
        unsigned short* Cb = (unsigned short*)Cout;
        #pragma unroll
        for (int m = 0; m < 8; ++m)
            #pragma unroll
            for (int j = 0; j < 4; ++j) {
                unsigned short* rp = Cb + (size_t)(r0 + m * 16 + j) * N;
                #pragma unroll
                for (int n = 0; n < 8; ++n)
                    rp[cb + n * 16] = f2bf_bits(acc[m][n][j] + bv[n]);
            }
    } else {
        float* Cf = (float*)Cout;
        #pragma unroll
        for (int m = 0; m < 8; ++m)
            #pragma unroll
            for (int j = 0; j < 4; ++j) {
                float* rp = Cf + (size_t)(r0 + m * 16 + j) * N;
                #pragma unroll
                for (int n = 0; n < 8; ++n)
                    rp[cb + n * 16] = acc[m][n][j] + bv[n];
            }
    }
}

// ---------------------------------------------------------------------------
// Per-position head attention (bf16 in, bf16 out). One block per position.
// R8: q_sq/k_sq folded into each thread's dot loop (identical LDS data, same
// value across threads) -> removes the t<32 serial phase and one barrier.
// ---------------------------------------------------------------------------
__global__ __launch_bounds__(256)
void attn_heads_kernel(const unsigned short* __restrict__ qkv,
                       unsigned short* __restrict__ aout)
{
    __shared__ float qs[16][68], ks[16][68], vs[16][68];
    __shared__ float attn_s[16][17];

    const int p = blockIdx.x;
    const int t = threadIdx.x;
    const short8v* rowv = (const short8v*)(qkv + (size_t)p * N_QKV);

    for (int c = t; c < N_QKV / 8; c += 256) {
        short8v v = rowv[c];
        int e0  = c << 3;
        int sec = e0 >> 10;
        int h   = (e0 >> 6) & 15;
        int d   = e0 & 63;
        float* dst = (sec == 0) ? &qs[h][d] : (sec == 1) ? &ks[h][d] : &vs[h][d];
        #pragma unroll
        for (int i = 0; i < 8; ++i)
            dst[i] = bf2f((unsigned short)v[i]);
    }
    __syncthreads();

    const int h = t >> 4;
    const int g = t & 15;
    float dot = 0.f, qq = 0.f, kk = 0.f;
    {
        const float* qr = qs[h];
        const float* kr = ks[g];
        #pragma unroll
        for (int d0 = 0; d0 < 64; d0 += 4) {
            float4 a = *(const float4*)(qr + d0);
            float4 b = *(const float4*)(kr + d0);
            dot = fmaf(a.x,b.x, fmaf(a.y,b.y, fmaf(a.z,b.z, fmaf(a.w,b.w, dot))));
            qq  = fmaf(a.x,a.x, fmaf(a.y,a.y, fmaf(a.z,a.z, fmaf(a.w,a.w, qq))));
            kk  = fmaf(b.x,b.x, fmaf(b.y,b.y, fmaf(b.z,b.z, fmaf(b.w,b.w, kk))));
        }
    }

    float dsq = fmaxf(qq + kk - 2.f * dot, 0.f);
    dsq = dsq * (1.f + CURV * cosf(sqrtf(dsq + EPS_F)));
    float force = sqrtf(qq) * sqrtf(kk) / (dsq + EPS_F);

    float m = force;
    #pragma unroll
    for (int off = 8; off >= 1; off >>= 1)
        m = fmaxf(m, __shfl_xor(m, off, 16));
    float e = expf(force - m);
    float ssum = e;
    #pragma unroll
    for (int off = 8; off >= 1; off >>= 1)
        ssum += __shfl_xor(ssum, off, 16);
    attn_s[h][g] = e / ssum;
    __syncthreads();

    const int d  = t & 63;
    const int hb = t >> 6;
    float o[4] = {0.f, 0.f, 0.f, 0.f};
    #pragma unroll
    for (int gg = 0; gg < 16; ++gg) {
        float vv = vs[gg][d];
        #pragma unroll
        for (int hh = 0; hh < 4; ++hh)
            o[hh] = fmaf(attn_s[hb + hh*4][gg], vv, o[hh]);
    }
    unsigned short* orow = aout + (size_t)p * D_MODEL;
    #pragma unroll
    for (int hh = 0; hh < 4; ++hh)
        orow[(hb + hh*4) * 64 + d] = f2bf_bits(o[hh]);
}

// ---------------------------------------------------------------------------
extern "C" void kernel_launch(void* const* d_in, const int* in_sizes, int n_in,
                              void* d_out, int out_size, void* d_ws, size_t ws_size,
                              hipStream_t stream)
{
    const float* x     = (const float*)d_in[0];   // 16384 x 1024
    const float* W_qkv = (const float*)d_in[1];   // 1024 x 3072
    const float* b_qkv = (const float*)d_in[2];   // 3072
    const float* W_out = (const float*)d_in[3];   // 1024 x 1024
    const float* b_out = (const float*)d_in[4];   // 1024
    float* out = (float*)d_out;                   // 16384 x 1024

    // workspace: [0,96M) qkv bf16 | [96M,128M) xb/ab bf16 | Wt1 6M | Wt2 2M
    char* ws = (char*)d_ws;
    unsigned short* qkvb = (unsigned short*)ws;
    unsigned short* xb   = (unsigned short*)(ws + (size_t)M_TOTAL * N_QKV * 2);
    unsigned short* ab   = xb;   // alias: xb dead after GEMM1
    unsigned short* Wt1  = (unsigned short*)(ws + (size_t)M_TOTAL * N_QKV * 2
                                                + (size_t)M_TOTAL * D_MODEL * 2);
    unsigned short* Wt2  = Wt1 + (size_t)N_QKV * D_MODEL;

    // 0a) cast x -> bf16
    {
        int ngroups = M_TOTAL * D_MODEL / 4;
        cast_f32_bf16<<<ngroups / 256, 256, 0, stream>>>(x, xb, ngroups);
    }
    // 0b) transpose+cast weights
    {
        dim3 g(N_QKV / 32, D_MODEL / 32);
        transpose_cast<<<g, 256, 0, stream>>>(W_qkv, Wt1, D_MODEL, N_QKV);
        dim3 g2(D_MODEL / 32, D_MODEL / 32);
        transpose_cast<<<g2, 256, 0, stream>>>(W_out, Wt2, D_MODEL, D_MODEL);
    }

    // 1) qkv = x @ W_qkv + b_qkv  (bf16 out) — 256x256, 768 wg
    {
        int nbx = N_QKV / 256;                 // 12
        int nwg = (M_TOTAL / 256) * nbx;       // 768 (%8==0)
        gemm_wt128<1><<<nwg, 256, 0, stream>>>(xb, Wt1, b_qkv, qkvb,
                                               M_TOTAL, N_QKV, D_MODEL, nbx);
    }

    // 2) per-position head attention (bf16 -> bf16)
    attn_heads_kernel<<<M_TOTAL, 256, 0, stream>>>(qkvb, ab);

    // 3) out = ab @ W_out + b_out  (fp32 out) — 256x256, 256 wg
    {
        int nbx = D_MODEL / 256;               // 4
        int nwg = (M_TOTAL / 256) * nbx;       // 256 (%8==0)
        gemm_wt128<0><<<nwg, 256, 0, stream>>>(ab, Wt2, b_out, out,
                                               M_TOTAL, D_MODEL, D_MODEL, nbx);
    }
}

// Round 9
// 191.407 us; speedup vs baseline: 1.3584x; 1.3584x over previous
//
#include <hip/hip_runtime.h>
#include <hip/hip_bf16.h>
#include <math.h>

#define M_TOTAL 16384   // B*S = 4*4096
#define D_MODEL 1024
#define N_QKV   3072
#define CURV    0.15f
#define EPS_F   1e-6f

typedef __attribute__((ext_vector_type(8))) short short8v;
typedef __attribute__((ext_vector_type(4))) float f32x4;

__device__ __forceinline__ void gl_lds16(const void* g, void* l) {
    __builtin_amdgcn_global_load_lds(
        (const __attribute__((address_space(1))) void*)g,
        (__attribute__((address_space(3))) void*)l, 16, 0, 0);
}
__device__ __forceinline__ unsigned short f2bf_bits(float x) {
    __hip_bfloat16 t = __float2bfloat16(x);
    return *(unsigned short*)&t;
}
__device__ __forceinline__ float bf2f(unsigned short u) {
    return __uint_as_float(((unsigned)u) << 16);
}

// ---------------------------------------------------------------------------
// cast fp32 -> bf16, 4 elems/thread
// ---------------------------------------------------------------------------
__global__ __launch_bounds__(256)
void cast_f32_bf16(const float* __restrict__ in, unsigned short* __restrict__ out,
                   int ngroups)
{
    int i = blockIdx.x * 256 + threadIdx.x;
    if (i >= ngroups) return;
    float4 u = ((const float4*)in)[i];
    ushort4 r;
    r.x = f2bf_bits(u.x); r.y = f2bf_bits(u.y);
    r.z = f2bf_bits(u.z); r.w = f2bf_bits(u.w);
    ((ushort4*)out)[i] = r;
}

// ---------------------------------------------------------------------------
// transpose + cast: W[K][N] fp32  ->  Wt[N][K] bf16.
// ---------------------------------------------------------------------------
__global__ __launch_bounds__(256)
void transpose_cast(const float* __restrict__ W, unsigned short* __restrict__ Wt,
                    int K, int N)
{
    __shared__ float tile[32][33];
    const int n0 = blockIdx.x * 32;
    const int k0 = blockIdx.y * 32;
    const int tx = threadIdx.x & 31;
    const int ty = threadIdx.x >> 5;
    #pragma unroll
    for (int i = 0; i < 32; i += 8)
        tile[ty + i][tx] = W[(size_t)(k0 + ty + i) * N + n0 + tx];
    __syncthreads();
    #pragma unroll
    for (int i = 0; i < 32; i += 8)
        Wt[(size_t)(n0 + ty + i) * K + k0 + tx] = f2bf_bits(tile[tx][ty + i]);
}

// ---------------------------------------------------------------------------
// 256x256 bf16 MFMA GEMM — register-pipelined 4-phase/K-tile (R5, best=119.5us
// GEMM1). UNCHANGED this round to isolate the attention rewrite.
// ---------------------------------------------------------------------------
template<int OUT_BF16>
__global__ __launch_bounds__(512, 2)
void gemm256_8ph(const unsigned short* __restrict__ A,
                 const unsigned short* __restrict__ Bt,
                 const float* __restrict__ bias,
                 void* __restrict__ Cout,
                 int M, int N, int K, int nbx)
{
    __shared__ __align__(16) short smem_s[65536];   // 128 KiB

    const int t    = threadIdx.x;
    const int w    = t >> 6;
    const int lane = t & 63;
    const int wm   = w >> 2;
    const int wn   = w & 3;
    const int lr   = lane & 15;
    const int hi   = lane >> 4;
    const int lo7  = lane & 7;

    const int nwg  = gridDim.x;
    const int orig = blockIdx.x;
    const int wgid = (orig & 7) * (nwg >> 3) + (orig >> 3);
    const int by = wgid / nbx, bx = wgid % nbx;
    const int bm0 = by * 256, bn0 = bx * 256;

    const int nt = K >> 6;

    const int srow = t >> 3;
    const int scol = ((t & 7) ^ (srow & 7)) * 8;
    const unsigned short* Ag = A  + (size_t)(bm0 + srow) * K + scol;
    const unsigned short* Bg = Bt + (size_t)(bn0 + srow) * K + scol;
    const int wbase = w * 1024;

    auto STAGE = [&](int which, int half, int tile) {
        const unsigned short* g0 = (which ? Bg : Ag)
                                 + (size_t)(half * 128) * K + (size_t)tile * 64;
        char* d0 = (char*)smem_s + ((tile & 1) * 65536 + which * 32768
                                    + half * 16384 + wbase);
        gl_lds16(g0,                d0);
        gl_lds16(g0 + (size_t)64*K, d0 + 8192);
    };

    short8v a[8][2], b[4][2];
    f32x4 acc[8][4] = {};

    auto LDA = [&](int buf, int m, int ks) {
        a[m][ks] = *(const short8v*)&smem_s[buf*32768 + wm*8192
                        + (m*16 + lr)*64 + (((ks*4 + hi) ^ lo7) * 8)];
    };
    auto LDB = [&](int buf, int n, int ks) {
        b[n][ks] = *(const short8v*)&smem_s[buf*32768 + 16384 + (wn>>1)*8192
                        + ((wn&1)*64 + n*16 + lr)*64 + (((ks*4 + hi) ^ lo7) * 8)];
    };
    auto QUAD = [&](int mlo, int nlo) {
        __builtin_amdgcn_s_setprio(1);
        #pragma unroll
        for (int mi = 0; mi < 4; ++mi)
            #pragma unroll
            for (int ni = 0; ni < 2; ++ni)
                #pragma unroll
                for (int ks = 0; ks < 2; ++ks)
                    acc[mlo+mi][nlo+ni] = __builtin_amdgcn_mfma_f32_16x16x32_bf16(
                        a[mlo+mi][ks], b[nlo+ni][ks], acc[mlo+mi][nlo+ni], 0, 0, 0);
        __builtin_amdgcn_s_setprio(0);
    };

    STAGE(0,0,0); STAGE(0,1,0); STAGE(1,0,0); STAGE(1,1,0);
    STAGE(0,0,1); STAGE(0,1,1); STAGE(1,0,1); STAGE(1,1,1);
    asm volatile("s_waitcnt vmcnt(8)" ::: "memory");
    __builtin_amdgcn_s_barrier();
    #pragma unroll
    for (int m = 0; m < 4; ++m) { LDA(0,m,0); LDA(0,m,1); }
    LDB(0,0,0); LDB(0,0,1); LDB(0,1,0); LDB(0,1,1);

    for (int T = 0; T < nt; ++T) {
        const int buf  = T & 1;
        const int nbuf = buf ^ 1;
        LDB(buf,2,0); LDB(buf,2,1); LDB(buf,3,0); LDB(buf,3,1);
        asm volatile("s_waitcnt lgkmcnt(4)" ::: "memory");
        __builtin_amdgcn_sched_barrier(0);
        QUAD(0,0);
        #pragma unroll
        for (int m = 4; m < 8; ++m) { LDA(buf,m,0); LDA(buf,m,1); }
        asm volatile("s_waitcnt lgkmcnt(8)" ::: "memory");
        __builtin_amdgcn_sched_barrier(0);
        QUAD(0,2);
        __builtin_amdgcn_s_barrier();
        if (T+2 < nt) { STAGE(1,0,T+2); STAGE(1,1,T+2); }
        asm volatile("s_waitcnt lgkmcnt(0)" ::: "memory");
        __builtin_amdgcn_sched_barrier(0);
        QUAD(4,0);
        __builtin_amdgcn_s_barrier();
        if (T+2 < nt) { STAGE(0,0,T+2); STAGE(0,1,T+2); }
        if (T+2 < nt) { asm volatile("s_waitcnt vmcnt(8)" ::: "memory"); }
        else          { asm volatile("s_waitcnt vmcnt(0)" ::: "memory"); }
        __builtin_amdgcn_s_barrier();
        if (T+1 < nt) {
            #pragma unroll
            for (int m = 0; m < 4; ++m) { LDA(nbuf,m,0); LDA(nbuf,m,1); }
            LDB(nbuf,0,0); LDB(nbuf,0,1); LDB(nbuf,1,0); LDB(nbuf,1,1);
        }
        __builtin_amdgcn_sched_barrier(0);
        QUAD(4,2);
    }

    const int r0 = bm0 + wm*128 + hi*4;
    const int cb = bn0 + wn*64 + lr;
    float bv[4];
    #pragma unroll
    for (int n = 0; n < 4; ++n) bv[n] = bias[cb + n*16];
    if (OUT_BF16) {
        unsigned short* Cb = (unsigned short*)Cout;
        #pragma unroll
        for (int m = 0; m < 8; ++m)
            #pragma unroll
            for (int j = 0; j < 4; ++j) {
                unsigned short* rp = Cb + (size_t)(r0 + m*16 + j) * N;
                #pragma unroll
                for (int n = 0; n < 4; ++n)
                    rp[cb + n*16] = f2bf_bits(acc[m][n][j] + bv[n]);
            }
    } else {
        float* Cf = (float*)Cout;
        #pragma unroll
        for (int m = 0; m < 8; ++m)
            #pragma unroll
            for (int j = 0; j < 4; ++j) {
                float* rp = Cf + (size_t)(r0 + m*16 + j) * N;
                #pragma unroll
                for (int n = 0; n < 4; ++n)
                    rp[cb + n*16] = acc[m][n][j] + bv[n];
            }
    }
}

// ---------------------------------------------------------------------------
// R9 attention: ONE WAVE PER POSITION, all-register, no LDS, no barriers.
// qkv row (bf16): q[16][64] | k[16][64] | v[16][64].
// S^T = K @ Q^T via 2x mfma_16x16x32_bf16 (A=k rows, B=q rows, both natural
// row-major; layouts identical to the working GEMM). Lane l: holds
// S^T[g=hi*4+j][h=lr] (hi=l>>4, lr=l&15). qsq/ksq from the loaded fragments +
// shfl_xor(16,32). Softmax over g: in-lane(4) + shfl_xor(16,32). PV via
// mfma_16x16x32_bf16 with A=P (K padded to 32: g>=16 lanes zeroed) and
// B-frag = V columns (u16 loads, L1-hot row). D[m=h][n=d] -> direct store.
// ---------------------------------------------------------------------------
__global__ __launch_bounds__(256)
void attn_mfma_kernel(const unsigned short* __restrict__ qkv,
                      unsigned short* __restrict__ aout)
{
    const int l  = threadIdx.x & 63;
    const int wv = threadIdx.x >> 6;
    const int p  = blockIdx.x * 4 + wv;
    const int lr = l & 15;
    const int hi = l >> 4;
    const unsigned short* base = qkv + (size_t)p * N_QKV;

    // ---- fragments: A=k rows, B=q rows (row = lr, k-elems = hi*8.. ) ----
    short8v qf0 = *(const short8v*)(base +        lr*64 +      hi*8);
    short8v qf1 = *(const short8v*)(base +        lr*64 + 32 + hi*8);
    short8v kf0 = *(const short8v*)(base + 1024 + lr*64 +      hi*8);
    short8v kf1 = *(const short8v*)(base + 1024 + lr*64 + 32 + hi*8);

    f32x4 s = {};
    s = __builtin_amdgcn_mfma_f32_16x16x32_bf16(kf0, qf0, s, 0, 0, 0);
    s = __builtin_amdgcn_mfma_f32_16x16x32_bf16(kf1, qf1, s, 0, 0, 0);
    // s[j] = q_{h=lr} . k_{g=hi*4+j}

    // ---- row norms from fragments (partial over this lane's 16 k-elems) ----
    float qsq = 0.f, ksq = 0.f;
    #pragma unroll
    for (int i = 0; i < 8; ++i) {
        float q0 = bf2f((unsigned short)qf0[i]), q1 = bf2f((unsigned short)qf1[i]);
        float k0 = bf2f((unsigned short)kf0[i]), k1 = bf2f((unsigned short)kf1[i]);
        qsq = fmaf(q0, q0, fmaf(q1, q1, qsq));
        ksq = fmaf(k0, k0, fmaf(k1, k1, ksq));
    }
    qsq += __shfl_xor(qsq, 16); qsq += __shfl_xor(qsq, 32);  // full, idx by lr=h
    ksq += __shfl_xor(ksq, 16); ksq += __shfl_xor(ksq, 32);  // full, idx by lr=g

    const float mq = sqrtf(qsq);

    // ---- forces + softmax over g (fixed h=lr) ----
    float P[4];
    #pragma unroll
    for (int j = 0; j < 4; ++j) {
        float ksg = __shfl(ksq, hi * 4 + j);           // ksq[g]
        float dsq = fmaxf(qsq + ksg - 2.f * s[j], 0.f);
        dsq = dsq * (1.f + CURV * cosf(sqrtf(dsq + EPS_F)));
        P[j] = mq * sqrtf(ksg) / (dsq + EPS_F);
    }
    float mx = fmaxf(fmaxf(P[0], P[1]), fmaxf(P[2], P[3]));
    mx = fmaxf(mx, __shfl_xor(mx, 16));
    mx = fmaxf(mx, __shfl_xor(mx, 32));
    float sm = 0.f;
    #pragma unroll
    for (int j = 0; j < 4; ++j) { P[j] = expf(P[j] - mx); sm += P[j]; }
    sm += __shfl_xor(sm, 16); sm += __shfl_xor(sm, 32);
    const float inv = 1.f / sm;

    // ---- pack P -> bf16 pairs; redistribute to PV A-frag layout ----
    // lane needs P[h=lr][g = hi*8 + 0..7]; source lanes lr+16*(2hi), lr+16*(2hi+1)
    unsigned int w0 = (unsigned)f2bf_bits(P[0] * inv)
                    | ((unsigned)f2bf_bits(P[1] * inv) << 16);
    unsigned int w1 = (unsigned)f2bf_bits(P[2] * inv)
                    | ((unsigned)f2bf_bits(P[3] * inv) << 16);
    const int s0 = lr + (((2 * hi)     & 3) << 4);
    const int s1 = lr + (((2 * hi + 1) & 3) << 4);
    unsigned int a0 = __shfl((int)w0, s0), a1 = __shfl((int)w1, s0);
    unsigned int a2 = __shfl((int)w0, s1), a3 = __shfl((int)w1, s1);
    if (hi >= 2) { a0 = a1 = a2 = a3 = 0; }            // K-pad: g>=16 -> 0
    unsigned int pa_u[4] = {a0, a1, a2, a3};
    short8v pa = *(short8v*)pa_u;

    // ---- PV: 4 d-chunks; B-frag = V columns (row n=lr -> d, k=g=hi*8+e) ----
    const unsigned short* vb = base + 2048;
    unsigned short* orow = aout + (size_t)p * D_MODEL;
    #pragma unroll
    for (int c = 0; c < 4; ++c) {
        unsigned int bu[4];
        #pragma unroll
        for (int e2 = 0; e2 < 4; ++e2) {
            int g0 = (hi * 8 + e2 * 2) & 15;           // &15: pad lanes read valid mem
            int g1 = (hi * 8 + e2 * 2 + 1) & 15;
            unsigned int lo = vb[g0 * 64 + c * 16 + lr];
            unsigned int hi16 = vb[g1 * 64 + c * 16 + lr];
            bu[e2] = lo | (hi16 << 16);
        }
        short8v bv = *(short8v*)bu;
        f32x4 o = {};
        o = __builtin_amdgcn_mfma_f32_16x16x32_bf16(pa, bv, o, 0, 0, 0);
        // o[j] = Out[h = hi*4+j][d = c*16 + lr]
        #pragma unroll
        for (int j = 0; j < 4; ++j)
            orow[(hi * 4 + j) * 64 + c * 16 + lr] = f2bf_bits(o[j]);
    }
}

// ---------------------------------------------------------------------------
extern "C" void kernel_launch(void* const* d_in, const int* in_sizes, int n_in,
                              void* d_out, int out_size, void* d_ws, size_t ws_size,
                              hipStream_t stream)
{
    const float* x     = (const float*)d_in[0];   // 16384 x 1024
    const float* W_qkv = (const float*)d_in[1];   // 1024 x 3072
    const float* b_qkv = (const float*)d_in[2];   // 3072
    const float* W_out = (const float*)d_in[3];   // 1024 x 1024
    const float* b_out = (const float*)d_in[4];   // 1024
    float* out = (float*)d_out;                   // 16384 x 1024

    // workspace: [0,96M) qkv bf16 | [96M,128M) xb/ab bf16 | Wt1 6M | Wt2 2M
    char* ws = (char*)d_ws;
    unsigned short* qkvb = (unsigned short*)ws;
    unsigned short* xb   = (unsigned short*)(ws + (size_t)M_TOTAL * N_QKV * 2);
    unsigned short* ab   = xb;   // alias: xb dead after GEMM1
    unsigned short* Wt1  = (unsigned short*)(ws + (size_t)M_TOTAL * N_QKV * 2
                                                + (size_t)M_TOTAL * D_MODEL * 2);
    unsigned short* Wt2  = Wt1 + (size_t)N_QKV * D_MODEL;

    // 0a) cast x -> bf16
    {
        int ngroups = M_TOTAL * D_MODEL / 4;
        cast_f32_bf16<<<ngroups / 256, 256, 0, stream>>>(x, xb, ngroups);
    }
    // 0b) transpose+cast weights
    {
        dim3 g(N_QKV / 32, D_MODEL / 32);
        transpose_cast<<<g, 256, 0, stream>>>(W_qkv, Wt1, D_MODEL, N_QKV);
        dim3 g2(D_MODEL / 32, D_MODEL / 32);
        transpose_cast<<<g2, 256, 0, stream>>>(W_out, Wt2, D_MODEL, D_MODEL);
    }

    // 1) qkv = x @ W_qkv + b_qkv  (bf16 out)
    {
        int nbx = N_QKV / 256;                 // 12
        int nwg = (M_TOTAL / 256) * nbx;       // 768 (%8==0)
        gemm256_8ph<1><<<nwg, 512, 0, stream>>>(xb, Wt1, b_qkv, qkvb,
                                                M_TOTAL, N_QKV, D_MODEL, nbx);
    }

    // 2) per-position head attention — 1 wave/position, 4 positions/block
    attn_mfma_kernel<<<M_TOTAL / 4, 256, 0, stream>>>(qkvb, ab);

    // 3) out = ab @ W_out + b_out  (fp32 out)
    {
        int nbx = D_MODEL / 256;               // 4
        int nwg = (M_TOTAL / 256) * nbx;       // 256 (%8==0)
        gemm256_8ph<0><<<nwg, 512, 0, stream>>>(ab, Wt2, b_out, out,
                                                M_TOTAL, D_MODEL, D_MODEL, nbx);
    }
}